// Round 2
// baseline (2110.472 us; speedup 1.0000x reference)
//
#include <hip/hip_runtime.h>

#define NN 100000
#define NE 1600000
#define NG 1000
#define ETOT (NE + NN)

// ---------- feature_fc: h0[N,8] = x[N,4] @ W.T + b ----------
__global__ void k_feat(const float* __restrict__ x, const float* __restrict__ ffw,
                       const float* __restrict__ ffb, float* __restrict__ h0) {
    int n = blockIdx.x * 256 + threadIdx.x;
    if (n >= NN) return;
    float xv[4];
#pragma unroll
    for (int k = 0; k < 4; k++) xv[k] = x[n * 4 + k];
#pragma unroll
    for (int o = 0; o < 8; o++) {
        float a = ffb[o];
#pragma unroll
        for (int k = 0; k < 4; k++) a = fmaf(xv[k], ffw[o * 4 + k], a);
        h0[n * 8 + o] = a;
    }
}

// ---------- h1[N,128] = h0 @ gat1_w.T ----------
__global__ void k_h1(const float* __restrict__ h0, const float* __restrict__ g1w,
                     float* __restrict__ h1) {
    int tid = blockIdx.x * 256 + threadIdx.x;  // N*128 exact
    int n = tid >> 7, j = tid & 127;
    const float* w = g1w + j * 8;
    const float* h = h0 + n * 8;
    float a = 0.f;
#pragma unroll
    for (int k = 0; k < 8; k++) a = fmaf(h[k], w[k], a);
    h1[tid] = a;
}

// ---------- per-node attention coefficients a_s,a_d [N,4] ----------
template <int C>
__global__ void k_att(const float* __restrict__ hbuf, const float* __restrict__ asw,
                      const float* __restrict__ adw, float* __restrict__ as_,
                      float* __restrict__ ad_) {
    int tid = blockIdx.x * 256 + threadIdx.x;
    if (tid >= NN * 4) return;
    int n = tid >> 2, h = tid & 3;
    const float* hp = hbuf + (size_t)n * (4 * C) + h * C;
    const float* ws_ = asw + h * C;
    const float* wd_ = adw + h * C;
    float a = 0.f, d = 0.f;
#pragma unroll
    for (int c = 0; c < C; c++) { a = fmaf(hp[c], ws_[c], a); d = fmaf(hp[c], wd_[c], d); }
    as_[tid] = a; ad_[tid] = d;
}

// ---------- CSR build over dst (self-loops appended) ----------
__global__ void k_count(const int* __restrict__ ei, int* __restrict__ deg) {
    int e = blockIdx.x * 256 + threadIdx.x;
    if (e >= ETOT) return;
    int dst = (e < NE) ? ei[NE + e] : (e - NE);
    atomicAdd(&deg[dst], 1);
}

__global__ void k_scan1(const int* __restrict__ deg, int* __restrict__ offs, int* __restrict__ bsum) {
    __shared__ int s[1024];
    int tid = threadIdx.x;
    int i = blockIdx.x * 1024 + tid;
    int v = (i < NN) ? deg[i] : 0;
    s[tid] = v;
    __syncthreads();
    for (int d = 1; d < 1024; d <<= 1) {
        int t = 0;
        if (tid >= d) t = s[tid - d];
        __syncthreads();
        if (tid >= d) s[tid] += t;
        __syncthreads();
    }
    if (i < NN) offs[i] = s[tid] - v;   // exclusive
    if (tid == 1023) bsum[blockIdx.x] = s[tid];
}

__global__ void k_scan2(int* __restrict__ bsum) {  // 1 block, 128 threads, 98 used
    __shared__ int s[128];
    int tid = threadIdx.x;
    int v = (tid < 98) ? bsum[tid] : 0;
    s[tid] = v;
    __syncthreads();
    for (int d = 1; d < 128; d <<= 1) {
        int t = 0;
        if (tid >= d) t = s[tid - d];
        __syncthreads();
        if (tid >= d) s[tid] += t;
        __syncthreads();
    }
    bsum[tid] = s[tid] - v;  // exclusive
}

__global__ void k_scan3(int* __restrict__ offs, const int* __restrict__ bsum, int* __restrict__ cur) {
    int i = blockIdx.x * 1024 + threadIdx.x;
    if (i < NN) {
        int v = offs[i] + bsum[blockIdx.x];
        offs[i] = v; cur[i] = v;
    }
    if (i == 0) offs[NN] = ETOT;
}

__global__ void k_scatter(const int* __restrict__ ei, int* __restrict__ cur, int* __restrict__ srcs) {
    int e = blockIdx.x * 256 + threadIdx.x;
    if (e >= ETOT) return;
    int src, dst;
    if (e < NE) { src = ei[e]; dst = ei[NE + e]; } else { src = dst = e - NE; }
    int p = atomicAdd(&cur[dst], 1);
    srcs[p] = src;
}

// ---------- GAT softmax-aggregation, one wave per dst node ----------
template <int HC>  // 128 (H=4,C=32) or 64 (H=4,C=16)
__global__ void k_gat_agg(const int* __restrict__ offs, const int* __restrict__ srcs,
                          const float* __restrict__ as_, const float* __restrict__ ad_,
                          const float* __restrict__ hbuf, const float* __restrict__ bias,
                          float* __restrict__ outb) {
    int wid = (blockIdx.x * 256 + threadIdx.x) >> 6;
    int lane = threadIdx.x & 63;
    if (wid >= NN) return;
    int off = offs[wid];
    int deg = offs[wid + 1] - off;
    float adn[4];
#pragma unroll
    for (int h = 0; h < 4; h++) adn[h] = ad_[wid * 4 + h];
    float mx[4] = {-1e30f, -1e30f, -1e30f, -1e30f};
    for (int base = 0; base < deg; base += 64) {
        int i = base + lane;
        if (i < deg) {
            int s = srcs[off + i];
#pragma unroll
            for (int h = 0; h < 4; h++) {
                float e = as_[s * 4 + h] + adn[h];
                e = e > 0.f ? e : 0.2f * e;
                mx[h] = fmaxf(mx[h], e);
            }
        }
    }
#pragma unroll
    for (int h = 0; h < 4; h++)
#pragma unroll
        for (int d = 32; d; d >>= 1) mx[h] = fmaxf(mx[h], __shfl_xor(mx[h], d, 64));
    float sm[4] = {0.f, 0.f, 0.f, 0.f};
    for (int base = 0; base < deg; base += 64) {
        int i = base + lane;
        if (i < deg) {
            int s = srcs[off + i];
#pragma unroll
            for (int h = 0; h < 4; h++) {
                float e = as_[s * 4 + h] + adn[h];
                e = e > 0.f ? e : 0.2f * e;
                sm[h] += __expf(e - mx[h]);
            }
        }
    }
#pragma unroll
    for (int h = 0; h < 4; h++)
#pragma unroll
        for (int d = 32; d; d >>= 1) sm[h] += __shfl_xor(sm[h], d, 64);

    if constexpr (HC == 128) {
        int hA = lane >> 5;  // head of channel `lane`; channel lane+64 -> head hA+2
        float mxA = hA ? mx[1] : mx[0], mxB = hA ? mx[3] : mx[2];
        float rdA = 1.f / (hA ? sm[1] : sm[0]), rdB = 1.f / (hA ? sm[3] : sm[2]);
        float adA = hA ? adn[1] : adn[0], adB = hA ? adn[3] : adn[2];
        float acc0 = 0.f, acc1 = 0.f;
        for (int k = 0; k < deg; k++) {
            int s = srcs[off + k];
            float e0 = as_[s * 4 + hA] + adA;       e0 = e0 > 0.f ? e0 : 0.2f * e0;
            float e1 = as_[s * 4 + hA + 2] + adB;   e1 = e1 > 0.f ? e1 : 0.2f * e1;
            float a0 = __expf(e0 - mxA) * rdA;
            float a1 = __expf(e1 - mxB) * rdB;
            const float* hr = hbuf + (size_t)s * 128;
            acc0 = fmaf(a0, hr[lane], acc0);
            acc1 = fmaf(a1, hr[lane + 64], acc1);
        }
        float v0 = acc0 + bias[lane];      v0 = v0 > 0.f ? v0 : 0.01f * v0;
        float v1 = acc1 + bias[lane + 64]; v1 = v1 > 0.f ? v1 : 0.01f * v1;
        outb[(size_t)wid * 128 + lane] = v0;
        outb[(size_t)wid * 128 + lane + 64] = v1;
    } else {
        int hd = lane >> 4;
        float mxA = (hd & 2) ? ((hd & 1) ? mx[3] : mx[2]) : ((hd & 1) ? mx[1] : mx[0]);
        float smA = (hd & 2) ? ((hd & 1) ? sm[3] : sm[2]) : ((hd & 1) ? sm[1] : sm[0]);
        float adA = (hd & 2) ? ((hd & 1) ? adn[3] : adn[2]) : ((hd & 1) ? adn[1] : adn[0]);
        float rdA = 1.f / smA;
        float acc0 = 0.f;
        for (int k = 0; k < deg; k++) {
            int s = srcs[off + k];
            float e0 = as_[s * 4 + hd] + adA; e0 = e0 > 0.f ? e0 : 0.2f * e0;
            float a0 = __expf(e0 - mxA) * rdA;
            acc0 = fmaf(a0, hbuf[(size_t)s * 64 + lane], acc0);
        }
        float v0 = acc0 + bias[lane]; v0 = v0 > 0.f ? v0 : 0.01f * v0;
        outb[(size_t)wid * 64 + lane] = v0;
    }
}

// ---------- h2[N,64] = g1 @ gat2_w.T ----------
__global__ void k_h2(const float* __restrict__ g1, const float* __restrict__ g2w,
                     float* __restrict__ h2) {
    int tid = blockIdx.x * 256 + threadIdx.x;  // N*64 exact
    int n = tid >> 6, j = tid & 63;
    const float* g = g1 + (size_t)n * 128;
    const float* w = g2w + j * 128;
    float a0 = 0.f, a1 = 0.f, a2 = 0.f, a3 = 0.f;
#pragma unroll
    for (int k = 0; k < 32; k++) {
        a0 = fmaf(g[4 * k], w[4 * k], a0);
        a1 = fmaf(g[4 * k + 1], w[4 * k + 1], a1);
        a2 = fmaf(g[4 * k + 2], w[4 * k + 2], a2);
        a3 = fmaf(g[4 * k + 3], w[4 * k + 3], a3);
    }
    h2[tid] = (a0 + a1) + (a2 + a3);
}

// ---------- precompute fused attention M^T (out@v) and bias ----------
__global__ void k_fuse(const float* __restrict__ enc_in_w, const float* __restrict__ enc_in_b,
                       const float* __restrict__ enc_out_w, const float* __restrict__ enc_out_b,
                       const float* __restrict__ sa_in_w, const float* __restrict__ sa_in_b,
                       const float* __restrict__ sa_out_w, const float* __restrict__ sa_out_b,
                       const float* __restrict__ ca_in_w, const float* __restrict__ ca_in_b,
                       const float* __restrict__ ca_out_w, const float* __restrict__ ca_out_b,
                       float* __restrict__ Mt, float* __restrict__ fb) {
    int tid = blockIdx.x * 256 + threadIdx.x;  // 6*64*64 = 24576 exact
    int p = tid >> 12, r = tid & 4095, j = r >> 6, k = r & 63;
    int li = p & 1;
    const float *iw, *ib, *ow, *ob;
    if (p < 2)      { iw = enc_in_w + li * 12288; ib = enc_in_b + li * 192; ow = enc_out_w + li * 4096; ob = enc_out_b + li * 64; }
    else if (p < 4) { iw = sa_in_w + li * 12288;  ib = sa_in_b + li * 192;  ow = sa_out_w + li * 4096;  ob = sa_out_b + li * 64; }
    else            { iw = ca_in_w + li * 12288;  ib = ca_in_b + li * 192;  ow = ca_out_w + li * 4096;  ob = ca_out_b + li * 64; }
    float a = 0.f;
    for (int m = 0; m < 64; m++) a = fmaf(ow[j * 64 + m], iw[(128 + m) * 64 + k], a);
    Mt[p * 4096 + k * 64 + j] = a;
    if (k == 0) {
        float fa = ob[j];
        for (int m = 0; m < 64; m++) fa = fmaf(ow[j * 64 + m], ib[128 + m], fa);
        fb[p * 64 + j] = fa;
    }
}

// ---------- transpose f2 weights: f2t[p][h*64+j] = f2[p][j*256+h] ----------
__global__ void k_f2t(const float* __restrict__ enc_f2_w, const float* __restrict__ dec_f2_w,
                      float* __restrict__ f2t) {
    int tid = blockIdx.x * 256 + threadIdx.x;  // 4*16384 = 65536 exact
    int p = tid >> 14, r = tid & 16383;
    int h = r >> 6, j = r & 63;
    const float* src = (p < 2) ? enc_f2_w + p * 16384 : dec_f2_w + (p - 2) * 16384;
    f2t[tid] = src[j * 256 + h];
}

// ---------- fused per-node transformer (2 enc + 2 dec layers) ----------
struct XParams {
    const float* Mt;   const float* fb;   const float* f2t;
    const float* ef1w; const float* ef1b; const float* ef2b;
    const float* df1w; const float* df1b; const float* df2b;
    const float* el1g; const float* el1b; const float* el2g; const float* el2b;
    const float* dl1g; const float* dl1b; const float* dl2g; const float* dl2b;
    const float* dl3g; const float* dl3b;
};

__device__ __forceinline__ void lnorm(float* y, const float* g, const float* b) {
    float s0 = 0.f, s1 = 0.f, s2 = 0.f, s3 = 0.f;
#pragma unroll
    for (int j = 0; j < 16; j++) {
        s0 += y[4 * j]; s1 += y[4 * j + 1]; s2 += y[4 * j + 2]; s3 += y[4 * j + 3];
    }
    float m = ((s0 + s1) + (s2 + s3)) * (1.f / 64.f);
    float v0 = 0.f, v1 = 0.f, v2 = 0.f, v3 = 0.f;
#pragma unroll
    for (int j = 0; j < 16; j++) {
        float d0 = y[4 * j] - m, d1 = y[4 * j + 1] - m, d2 = y[4 * j + 2] - m, d3 = y[4 * j + 3] - m;
        v0 = fmaf(d0, d0, v0); v1 = fmaf(d1, d1, v1); v2 = fmaf(d2, d2, v2); v3 = fmaf(d3, d3, v3);
    }
    float r = rsqrtf(fmaf((v0 + v1) + (v2 + v3), 1.f / 64.f, 1e-5f));
#pragma unroll
    for (int j = 0; j < 64; j++) y[j] = fmaf((y[j] - m) * r, g[j], b[j]);
}

__global__ __launch_bounds__(256) void k_xform(float* __restrict__ yio, XParams P) {
    __shared__ float lsc[256 * 17];
    int t = threadIdx.x;
    int node = blockIdx.x * 256 + t;
    if (node >= NN) return;
    float y[64];
    {
        const float4* yin = (const float4*)(yio + (size_t)node * 64);
#pragma unroll
        for (int q = 0; q < 16; q++) {
            float4 v = yin[q];
            y[4 * q] = v.x; y[4 * q + 1] = v.y; y[4 * q + 2] = v.z; y[4 * q + 3] = v.w;
        }
    }
    float* ls = lsc + t * 17;  // padded private LDS scratch: conflict-free dynamic y[k] access
#pragma unroll 1
    for (int layer = 0; layer < 4; layer++) {
        const bool enc = layer < 2;
        const int li = enc ? layer : layer - 2;
        const int nat = enc ? 1 : 2;
#pragma unroll 1
        for (int at = 0; at < nat; at++) {
            int p = enc ? layer : (at == 0 ? 2 + li : 4 + li);
            const float* M = P.Mt + p * 4096;
            {
                const float* fp = P.fb + p * 64;
                float acc[64];
#pragma unroll
                for (int j = 0; j < 64; j++) acc[j] = fp[j];
#pragma unroll
                for (int ch = 0; ch < 4; ch++) {
#pragma unroll
                    for (int u = 0; u < 16; u++) ls[u] = y[ch * 16 + u];
#pragma unroll 1
                    for (int k2 = 0; k2 < 16; k2++) {
                        float yk = ls[k2];
                        const float* Mr = M + (ch * 16 + k2) * 64;
#pragma unroll
                        for (int j = 0; j < 64; j++) acc[j] = fmaf(yk, Mr[j], acc[j]);
                    }
                }
#pragma unroll
                for (int j = 0; j < 64; j++) y[j] += acc[j];
            }
            const float* g; const float* b;
            if (enc)          { g = P.el1g + li * 64; b = P.el1b + li * 64; }
            else if (at == 0) { g = P.dl1g + li * 64; b = P.dl1b + li * 64; }
            else              { g = P.dl2g + li * 64; b = P.dl2b + li * 64; }
            lnorm(y, g, b);
        }
        // FFN 64 -> 256 -> 64
        const float* f1  = (enc ? P.ef1w : P.df1w) + li * 16384;
        const float* f1b = (enc ? P.ef1b : P.df1b) + li * 256;
        const float* f2r = P.f2t + (enc ? layer : 2 + li) * 16384;
        const float* f2b = (enc ? P.ef2b : P.df2b) + li * 64;
        {
            float acc[64];
#pragma unroll
            for (int j = 0; j < 64; j++) acc[j] = f2b[j];
#pragma unroll 1
            for (int h = 0; h < 256; h++) {
                const float* fr = f1 + h * 64;
                float h0 = 0.f, h1 = 0.f, h2 = 0.f, h3 = 0.f;
#pragma unroll
                for (int k = 0; k < 16; k++) {
                    h0 = fmaf(y[4 * k], fr[4 * k], h0);
                    h1 = fmaf(y[4 * k + 1], fr[4 * k + 1], h1);
                    h2 = fmaf(y[4 * k + 2], fr[4 * k + 2], h2);
                    h3 = fmaf(y[4 * k + 3], fr[4 * k + 3], h3);
                }
                float hh = f1b[h] + ((h0 + h1) + (h2 + h3));
                hh = fmaxf(hh, 0.f);
                const float* ft = f2r + h * 64;
#pragma unroll
                for (int j = 0; j < 64; j++) acc[j] = fmaf(hh, ft[j], acc[j]);
            }
#pragma unroll
            for (int j = 0; j < 64; j++) y[j] += acc[j];
        }
        const float* g2 = (enc ? P.el2g : P.dl3g) + li * 64;
        const float* b2 = (enc ? P.el2b : P.dl3b) + li * 64;
        lnorm(y, g2, b2);
    }
    {
        float4* yo = (float4*)(yio + (size_t)node * 64);
#pragma unroll
        for (int q = 0; q < 16; q++) {
            float4 v;
            v.x = y[4 * q]; v.y = y[4 * q + 1]; v.z = y[4 * q + 2]; v.w = y[4 * q + 3];
            yo[q] = v;
        }
    }
}

// ---------- global mean pool (batch is sorted) ----------
__global__ void k_pool(const float* __restrict__ y, const int* __restrict__ batch,
                       float* __restrict__ pooled) {
    int wid = (blockIdx.x * 256 + threadIdx.x) >> 6;
    int lane = threadIdx.x & 63;
    if (wid >= NG) return;
    int lo = 0, hi = NN;
    while (lo < hi) { int mid = (lo + hi) >> 1; if (batch[mid] < wid) lo = mid + 1; else hi = mid; }
    int st = lo;
    hi = NN;
    while (lo < hi) { int mid = (lo + hi) >> 1; if (batch[mid] < wid + 1) lo = mid + 1; else hi = mid; }
    int en = lo;
    float s = 0.f;
    for (int i = st; i < en; i++) s += y[(size_t)i * 64 + lane];
    int cnt = en - st; if (cnt < 1) cnt = 1;
    pooled[wid * 64 + lane] = s / (float)cnt;
}

// ---------- final fc: out[G,33] = pooled @ fc_w.T + fc_b ----------
__global__ void k_fc(const float* __restrict__ pooled, const float* __restrict__ fcw,
                     const float* __restrict__ fcb, float* __restrict__ out) {
    int tid = blockIdx.x * 256 + threadIdx.x;
    if (tid >= NG * 33) return;
    int g = tid / 33, o = tid - g * 33;
    const float* p = pooled + g * 64;
    const float* w = fcw + o * 64;
    float a0 = 0.f, a1 = 0.f, a2 = 0.f, a3 = 0.f;
#pragma unroll
    for (int k = 0; k < 16; k++) {
        a0 = fmaf(p[4 * k], w[4 * k], a0);
        a1 = fmaf(p[4 * k + 1], w[4 * k + 1], a1);
        a2 = fmaf(p[4 * k + 2], w[4 * k + 2], a2);
        a3 = fmaf(p[4 * k + 3], w[4 * k + 3], a3);
    }
    out[tid] = fcb[o] + (a0 + a1) + (a2 + a3);
}

extern "C" void kernel_launch(void* const* d_in, const int* in_sizes, int n_in,
                              void* d_out, int out_size, void* d_ws, size_t ws_size,
                              hipStream_t stream) {
    (void)in_sizes; (void)n_in; (void)out_size; (void)ws_size;
    char* ws = (char*)d_ws;
    size_t o = 0;
    auto A = [&](size_t b) { size_t r = o; o += (b + 255) & ~(size_t)255; return r; };
    float* f_h0  = (float*)(ws + A((size_t)NN * 8 * 4));
    float* f_h1  = (float*)(ws + A((size_t)NN * 128 * 4));  // reused as h2 ([N,64])
    float* f_as1 = (float*)(ws + A((size_t)NN * 4 * 4));
    float* f_ad1 = (float*)(ws + A((size_t)NN * 4 * 4));
    float* f_as2 = (float*)(ws + A((size_t)NN * 4 * 4));
    float* f_ad2 = (float*)(ws + A((size_t)NN * 4 * 4));
    float* f_g1  = (float*)(ws + A((size_t)NN * 128 * 4));  // reused as g2out / y ([N,64])
    int* i_off   = (int*)(ws + A((size_t)(NN + 1) * 4));
    int* i_cur   = (int*)(ws + A((size_t)NN * 4));
    int* i_deg   = (int*)(ws + A((size_t)NN * 4));
    int* i_bsum  = (int*)(ws + A((size_t)1024 * 4));
    int* i_srcs  = (int*)(ws + A((size_t)ETOT * 4));
    float* f_Mt  = (float*)(ws + A((size_t)6 * 4096 * 4));
    float* f_fb  = (float*)(ws + A((size_t)6 * 64 * 4));
    float* f_f2t = (float*)(ws + A((size_t)4 * 16384 * 4));
    float* f_pool= (float*)(ws + A((size_t)NG * 64 * 4));

    const float* x   = (const float*)d_in[0];
    const int* ei    = (const int*)d_in[1];
    const int* batch = (const int*)d_in[2];
    #define F32(i) ((const float*)d_in[i])

    hipMemsetAsync(i_deg, 0, (size_t)NN * 4, stream);
    k_feat<<<(NN + 255) / 256, 256, 0, stream>>>(x, F32(3), F32(4), f_h0);
    k_h1<<<NN * 128 / 256, 256, 0, stream>>>(f_h0, F32(5), f_h1);
    k_att<32><<<(NN * 4 + 255) / 256, 256, 0, stream>>>(f_h1, F32(6), F32(7), f_as1, f_ad1);
    k_count<<<(ETOT + 255) / 256, 256, 0, stream>>>(ei, i_deg);
    k_scan1<<<98, 1024, 0, stream>>>(i_deg, i_off, i_bsum);
    k_scan2<<<1, 128, 0, stream>>>(i_bsum);
    k_scan3<<<98, 1024, 0, stream>>>(i_off, i_bsum, i_cur);
    k_scatter<<<(ETOT + 255) / 256, 256, 0, stream>>>(ei, i_cur, i_srcs);
    k_gat_agg<128><<<NN * 64 / 256, 256, 0, stream>>>(i_off, i_srcs, f_as1, f_ad1, f_h1, F32(8), f_g1);
    k_h2<<<NN * 64 / 256, 256, 0, stream>>>(f_g1, F32(9), f_h1);  // h2 -> f_h1
    k_att<16><<<(NN * 4 + 255) / 256, 256, 0, stream>>>(f_h1, F32(10), F32(11), f_as2, f_ad2);
    k_gat_agg<64><<<NN * 64 / 256, 256, 0, stream>>>(i_off, i_srcs, f_as2, f_ad2, f_h1, F32(12), f_g1);
    k_fuse<<<24576 / 256, 256, 0, stream>>>(F32(13), F32(14), F32(15), F32(16),
                                            F32(25), F32(26), F32(27), F32(28),
                                            F32(29), F32(30), F32(31), F32(32),
                                            f_Mt, f_fb);
    k_f2t<<<65536 / 256, 256, 0, stream>>>(F32(19), F32(35), f_f2t);
    XParams P;
    P.Mt = f_Mt; P.fb = f_fb; P.f2t = f_f2t;
    P.ef1w = F32(17); P.ef1b = F32(18); P.ef2b = F32(20);
    P.df1w = F32(33); P.df1b = F32(34); P.df2b = F32(36);
    P.el1g = F32(21); P.el1b = F32(22); P.el2g = F32(23); P.el2b = F32(24);
    P.dl1g = F32(37); P.dl1b = F32(38); P.dl2g = F32(39); P.dl2b = F32(40);
    P.dl3g = F32(41); P.dl3b = F32(42);
    k_xform<<<(NN + 255) / 256, 256, 0, stream>>>(f_g1, P);
    k_pool<<<NG * 64 / 256, 256, 0, stream>>>(f_g1, batch, f_pool);
    k_fc<<<(NG * 33 + 255) / 256, 256, 0, stream>>>(f_pool, F32(43), F32(44), (float*)d_out);
    #undef F32
}